// Round 7
// baseline (235.171 us; speedup 1.0000x reference)
//
#include <hip/hip_runtime.h>
#include <math.h>

#define C 8192
#define D 1024
#define BATCH 1024
#define PM 0.95f
#define PMC 0.05f
// values pre-scaled by 8 before fp8 quant; dot comes out 64x too big.
// epilogue uses 10/64 = 0.15625 (exact in fp32).
#define INVT_SCALED 0.15625f

typedef unsigned char u8;
typedef __attribute__((ext_vector_type(16))) float f32x16;

// ---------------------------------------------------------------------------
// EMA + fp8 quantize, ONE WAVE PER CLASS (4 classes/block, 2048 blocks).
// No block barriers after the label stage; match list via ballot (ascending
// sample order: base ascending, lowest-lane-first), norm via wave shuffles.
// fp8 layout (verified rounds 5-6): element (row c, k) ->
//   P8[(c>>5)*32768 + (k>>4)*512 + ((k>>3)&1)*256 + (c&31)*8 + (k&7)]
__global__ __launch_bounds__(256) void ema_split_kernel(const float* __restrict__ feat,
                                                        const int* __restrict__ labels,
                                                        const float* __restrict__ protos,
                                                        u8* __restrict__ P8,
                                                        float* __restrict__ rowsum,
                                                        float* __restrict__ out) {
    __shared__ int sl[BATCH];
    const int t = threadIdx.x, w = t >> 6, lane = t & 63;
    const int c = blockIdx.x * 4 + w;

    if (blockIdx.x < 32) rowsum[blockIdx.x * 256 + t] = 0.0f;
    if (blockIdx.x == 0 && t == 0) out[0] = 0.0f;

    for (int i = t; i < BATCH; i += 256) sl[i] = labels[i];
    __syncthreads();

    // lane holds k in {s*256 + lane*4 .. +4} for s=0..3 (coalesced float4 loads)
    float4 v[4];
    #pragma unroll
    for (int s = 0; s < 4; ++s)
        v[s] = *(const float4*)(protos + (size_t)c * D + s * 256 + lane * 4);

    for (int base = 0; base < BATCH; base += 64) {
        unsigned long long mask = __ballot(sl[base + lane] == c);
        while (mask) {
            const int b = __ffsll((long long)mask) - 1;
            mask &= mask - 1;
            const int idx = base + b;
            float ss = 0.0f;
            #pragma unroll
            for (int s = 0; s < 4; ++s) {
                const float4 f = *(const float4*)(feat + (size_t)idx * D + s * 256 + lane * 4);
                v[s].x = v[s].x * PM + f.x * PMC;
                v[s].y = v[s].y * PM + f.y * PMC;
                v[s].z = v[s].z * PM + f.z * PMC;
                v[s].w = v[s].w * PM + f.w * PMC;
                ss += v[s].x * v[s].x + v[s].y * v[s].y + v[s].z * v[s].z + v[s].w * v[s].w;
            }
            #pragma unroll
            for (int off = 32; off > 0; off >>= 1) ss += __shfl_xor(ss, off);
            const float inv = 1.0f / fmaxf(sqrtf(ss), 1e-12f);
            #pragma unroll
            for (int s = 0; s < 4; ++s) {
                v[s].x *= inv; v[s].y *= inv; v[s].z *= inv; v[s].w *= inv;
            }
        }
    }

    // quantize (x8 pre-scale, RNE) + store 4 consecutive k per uint
    u8* ob = P8 + (size_t)(c >> 5) * 32768 + (c & 31) * 8;
    #pragma unroll
    for (int s = 0; s < 4; ++s) {
        const int k0 = s * 256 + lane * 4;
        const size_t off = (size_t)(k0 >> 4) * 512 + ((k0 >> 3) & 1) * 256 + (k0 & 7);
        int p = __builtin_amdgcn_cvt_pk_fp8_f32(v[s].x * 8.0f, v[s].y * 8.0f, 0, false);
        p = __builtin_amdgcn_cvt_pk_fp8_f32(v[s].z * 8.0f, v[s].w * 8.0f, p, true);
        *(unsigned int*)(ob + off) = (unsigned int)p;
    }
}

// ---------------------------------------------------------------------------
// fp8 Gram, mfma_f32_32x32x16_fp8_fp8, REGISTER-DIRECT K-loop: fragments are
// coalesced 512-B global reads (base + lane*8) served by L1/L2 (8 MB dataset);
// no LDS staging, NO barriers in the K-loop -> no vmcnt(0) drains, waves
// free-run. Two register sets, prefetch K-step ku+1/ku+2 while MFMAing ku.
// Block tile 256x256, 512 threads = 8 waves (qi=w&1: 128 rows, qj=w>>1: 64
// cols), wave tile 128x64 = 4x2 tiles of 32x32 (128 AGPR acc, 12 operand
// VGPRs/set). Triangle cover bj>=bi (528 blocks); diag blocks mask li>=lj ->
// rowsum == sum_neg exactly. XCD swizzle: blockIdx%8 owns strips
// {r,31-r,r+8,23-r} (66 blocks each, balanced) for L2 locality.
__global__ __launch_bounds__(512, 2) void gram8_kernel(const u8* __restrict__ P8,
                                                       float* __restrict__ rowsum) {
    __shared__ float rpart[256];
    __shared__ float cpart[256];
    const int t = threadIdx.x, w = t >> 6, lane = t & 63;

    // swizzled block -> (bi, bj)
    const int r = blockIdx.x & 7, m = blockIdx.x >> 3;
    const int m0 = 32 - r, m1 = m0 + r + 1, m2 = m1 + 24 - r;
    int bi, bj;
    if (m < m0)      { bi = r;      bj = bi + m; }
    else if (m < m1) { bi = 31 - r; bj = bi + (m - m0); }
    else if (m < m2) { bi = r + 8;  bj = bi + (m - m1); }
    else             { bi = 23 - r; bj = bi + (m - m2); }
    const bool diag = (bi == bj);

    if (t < 256) { rpart[t] = 0.0f; cpart[t] = 0.0f; }

    const int qi = w & 1, qj = w >> 1;
    const u8* pa[4];
    const u8* pb[2];
    #pragma unroll
    for (int ti = 0; ti < 4; ++ti)
        pa[ti] = P8 + (size_t)(bi * 8 + qi * 4 + ti) * 32768 + lane * 8;
    #pragma unroll
    for (int tj = 0; tj < 2; ++tj)
        pb[tj] = P8 + (size_t)(bj * 8 + qj * 2 + tj) * 32768 + lane * 8;

    f32x16 acc[4][2];
    #pragma unroll
    for (int a = 0; a < 4; ++a)
        #pragma unroll
        for (int b = 0; b < 2; ++b)
            #pragma unroll
            for (int e = 0; e < 16; ++e) acc[a][b][e] = 0.0f;

    // software pipeline: set0 <- ku, set1 <- ku+1; 64 K-steps of K=16
    long a0[4], b0[2], a1[4], b1[2];
    #pragma unroll
    for (int ti = 0; ti < 4; ++ti) a0[ti] = *(const long*)(pa[ti]);
    #pragma unroll
    for (int tj = 0; tj < 2; ++tj) b0[tj] = *(const long*)(pb[tj]);

    for (int it = 0; it < 31; ++it) {
        #pragma unroll
        for (int ti = 0; ti < 4; ++ti) a1[ti] = *(const long*)(pa[ti] + 512);
        #pragma unroll
        for (int tj = 0; tj < 2; ++tj) b1[tj] = *(const long*)(pb[tj] + 512);
        #pragma unroll
        for (int ti = 0; ti < 4; ++ti)
            #pragma unroll
            for (int tj = 0; tj < 2; ++tj)
                acc[ti][tj] = __builtin_amdgcn_mfma_f32_32x32x16_fp8_fp8(
                    a0[ti], b0[tj], acc[ti][tj], 0, 0, 0);
        #pragma unroll
        for (int ti = 0; ti < 4; ++ti) { pa[ti] += 1024; a0[ti] = *(const long*)(pa[ti]); }
        #pragma unroll
        for (int tj = 0; tj < 2; ++tj) { pb[tj] += 1024; b0[tj] = *(const long*)(pb[tj]); }
        #pragma unroll
        for (int ti = 0; ti < 4; ++ti)
            #pragma unroll
            for (int tj = 0; tj < 2; ++tj)
                acc[ti][tj] = __builtin_amdgcn_mfma_f32_32x32x16_fp8_fp8(
                    a1[ti], b1[tj], acc[ti][tj], 0, 0, 0);
    }
    // tail: set0 holds ku=62; load ku=63, compute both
    #pragma unroll
    for (int ti = 0; ti < 4; ++ti) a1[ti] = *(const long*)(pa[ti] + 512);
    #pragma unroll
    for (int tj = 0; tj < 2; ++tj) b1[tj] = *(const long*)(pb[tj] + 512);
    #pragma unroll
    for (int ti = 0; ti < 4; ++ti)
        #pragma unroll
        for (int tj = 0; tj < 2; ++tj) {
            acc[ti][tj] = __builtin_amdgcn_mfma_f32_32x32x16_fp8_fp8(
                a0[ti], b0[tj], acc[ti][tj], 0, 0, 0);
            acc[ti][tj] = __builtin_amdgcn_mfma_f32_32x32x16_fp8_fp8(
                a1[ti], b1[tj], acc[ti][tj], 0, 0, 0);
        }

    // epilogue: exp(acc*10/64), diag-block triangle mask, row/col partials
    // C layout (32x32): col = lane&31, row = (reg&3) + 8*(reg>>2) + 4*(lane>>5)
    __syncthreads();   // rpart/cpart zeroed before use
    const int half = lane >> 5, col = lane & 31;
    float csum[2] = {0.0f, 0.0f};
    #pragma unroll
    for (int ti = 0; ti < 4; ++ti) {
        float rs[16];
        #pragma unroll
        for (int reg = 0; reg < 16; ++reg) rs[reg] = 0.0f;
        #pragma unroll
        for (int tj = 0; tj < 2; ++tj) {
            const int lj = qj * 64 + tj * 32 + col;
            #pragma unroll
            for (int reg = 0; reg < 16; ++reg) {
                const int li = qi * 128 + ti * 32 + (reg & 3) + 8 * (reg >> 2) + 4 * half;
                float e = __expf(acc[ti][tj][reg] * INVT_SCALED);
                if (diag && li >= lj) e = 0.0f;      // bi<bj blocks: always li<lj globally
                rs[reg] += e;
                csum[tj] += e;
            }
        }
        #pragma unroll
        for (int reg = 0; reg < 16; ++reg) {
            float v = rs[reg];
            v += __shfl_xor(v, 1); v += __shfl_xor(v, 2); v += __shfl_xor(v, 4);
            v += __shfl_xor(v, 8); v += __shfl_xor(v, 16);
            if (col == 0)
                atomicAdd(&rpart[qi * 128 + ti * 32 + (reg & 3) + 8 * (reg >> 2) + 4 * half], v);
        }
    }
    #pragma unroll
    for (int tj = 0; tj < 2; ++tj) {
        float v = csum[tj];
        v += __shfl_xor(v, 32);
        if (half == 0) atomicAdd(&cpart[qj * 64 + tj * 32 + col], v);
    }
    __syncthreads();
    if (t < 256) atomicAdd(&rowsum[bi * 256 + t], rpart[t]);
    else         atomicAdd(&rowsum[bj * 256 + (t - 256)], cpart[t - 256]);
}

// ---------------------------------------------------------------------------
// rowsum == sum_neg (diag + lower triangle excluded in gram)
__global__ __launch_bounds__(256) void final2_kernel(const float* __restrict__ rowsum,
                                                     float* __restrict__ out) {
    __shared__ float red[4];
    const int t = threadIdx.x;
    const int i = blockIdx.x * 256 + t;
    float v = logf(rowsum[i] * (1.0f / (float)(C - 1)));
    #pragma unroll
    for (int off = 32; off > 0; off >>= 1) v += __shfl_down(v, off);
    if ((t & 63) == 0) red[t >> 6] = v;
    __syncthreads();
    if (t == 0)
        atomicAdd(out, (red[0] + red[1] + red[2] + red[3]) * (1.0f / (float)C));
}

// ---------------------------------------------------------------------------
extern "C" void kernel_launch(void* const* d_in, const int* in_sizes, int n_in,
                              void* d_out, int out_size, void* d_ws, size_t ws_size,
                              hipStream_t stream) {
    const float* feat = (const float*)d_in[0];
    const int* labels = (const int*)d_in[1];
    const float* protos = (const float*)d_in[2];
    float* out = (float*)d_out;
    float* rowsum = (float*)d_ws;               // 32 KB
    u8* P8 = (u8*)((char*)d_ws + 32768);        // 8 MiB packed fp8 protos

    ema_split_kernel<<<C / 4, 256, 0, stream>>>(feat, labels, protos, P8, rowsum, out);
    gram8_kernel<<<528, 512, 0, stream>>>(P8, rowsum);
    final2_kernel<<<C / 256, 256, 0, stream>>>(rowsum, out);
}

// Round 8
// 153.255 us; speedup vs baseline: 1.5345x; 1.5345x over previous
//
#include <hip/hip_runtime.h>
#include <math.h>

#define C 8192
#define D 1024
#define BATCH 1024
#define PM 0.95f
#define PMC 0.05f
// values pre-scaled by 8 before fp8 quant; dot comes out 64x too big.
// epilogue uses 10/64 = 0.15625 (exact in fp32).
#define INVT_SCALED 0.15625f

typedef unsigned char u8;
typedef __attribute__((ext_vector_type(16))) float f32x16;

#define GLOBAL_AS(p) ((const __attribute__((address_space(1))) void*)(p))
#define LDS_AS(p) ((__attribute__((address_space(3))) void*)(p))

// ---------------------------------------------------------------------------
// EMA + fp8 quantize, one wave per class (4 classes/block). Verified round 7.
// fp8 layout: element (row c, k) ->
//   P8[(c>>5)*32768 + (k>>4)*512 + ((k>>3)&1)*256 + (c&31)*8 + (k&7)]
__global__ __launch_bounds__(256) void ema_split_kernel(const float* __restrict__ feat,
                                                        const int* __restrict__ labels,
                                                        const float* __restrict__ protos,
                                                        u8* __restrict__ P8,
                                                        float* __restrict__ rowsum,
                                                        float* __restrict__ out) {
    __shared__ int sl[BATCH];
    const int t = threadIdx.x, w = t >> 6, lane = t & 63;
    const int c = blockIdx.x * 4 + w;

    if (blockIdx.x < 32) rowsum[blockIdx.x * 256 + t] = 0.0f;
    if (blockIdx.x == 0 && t == 0) out[0] = 0.0f;

    for (int i = t; i < BATCH; i += 256) sl[i] = labels[i];
    __syncthreads();

    float4 v[4];
    #pragma unroll
    for (int s = 0; s < 4; ++s)
        v[s] = *(const float4*)(protos + (size_t)c * D + s * 256 + lane * 4);

    for (int base = 0; base < BATCH; base += 64) {
        unsigned long long mask = __ballot(sl[base + lane] == c);
        while (mask) {
            const int b = __ffsll((long long)mask) - 1;
            mask &= mask - 1;
            const int idx = base + b;
            float ss = 0.0f;
            #pragma unroll
            for (int s = 0; s < 4; ++s) {
                const float4 f = *(const float4*)(feat + (size_t)idx * D + s * 256 + lane * 4);
                v[s].x = v[s].x * PM + f.x * PMC;
                v[s].y = v[s].y * PM + f.y * PMC;
                v[s].z = v[s].z * PM + f.z * PMC;
                v[s].w = v[s].w * PM + f.w * PMC;
                ss += v[s].x * v[s].x + v[s].y * v[s].y + v[s].z * v[s].z + v[s].w * v[s].w;
            }
            #pragma unroll
            for (int off = 32; off > 0; off >>= 1) ss += __shfl_xor(ss, off);
            const float inv = 1.0f / fmaxf(sqrtf(ss), 1e-12f);
            #pragma unroll
            for (int s = 0; s < 4; ++s) {
                v[s].x *= inv; v[s].y *= inv; v[s].z *= inv; v[s].w *= inv;
            }
        }
    }

    u8* ob = P8 + (size_t)(c >> 5) * 32768 + (c & 31) * 8;
    #pragma unroll
    for (int s = 0; s < 4; ++s) {
        const int k0 = s * 256 + lane * 4;
        const size_t off = (size_t)(k0 >> 4) * 512 + ((k0 >> 3) & 1) * 256 + (k0 & 7);
        int p = __builtin_amdgcn_cvt_pk_fp8_f32(v[s].x * 8.0f, v[s].y * 8.0f, 0, false);
        p = __builtin_amdgcn_cvt_pk_fp8_f32(v[s].z * 8.0f, v[s].w * 8.0f, p, true);
        *(unsigned int*)(ob + off) = (unsigned int)p;
    }
}

// ---------------------------------------------------------------------------
// fp8 Gram, mfma_f32_32x32x16_fp8_fp8. OCCUPANCY-FIRST layout: 128x128 block
// tile, 256 threads = 4 waves in 2x2, wave tile 64x64 = 2x2 tiles of 32x32
// (64 AGPR acc) -> ~115 regs/wave -> 4 waves/SIMD -> 4 blocks/CU; barrier
// drains of one block overlap compute of three others (r2's mechanism).
// Double-buffered LDS (16 KB/buf), ONE barrier per BK=64 chunk: staging for
// chunk kc+1 issued right after barrier kc, drained at barrier kc+1 (a full
// chunk of compute in flight). Triangle cover bi<=bj over 64 strips of 128
// rows (2080 blocks); diag blocks mask li>=lj -> rowsum == sum_neg exactly.
// XCD swizzle: XCD r owns strips {r,15-r,16+r,31-r,32+r,47-r,48+r,63-r}
// (exactly 260 blocks each).
__global__ __launch_bounds__(256, 4) void gram8_kernel(const u8* __restrict__ P8,
                                                       float* __restrict__ rowsum) {
    __shared__ u8 lds[2][16384];     // per buf: A units 0..15 @ ua*512, B @ 8192+
    __shared__ float rpart[128];
    __shared__ float cpart[128];
    const int t = threadIdx.x, w = t >> 6, lane = t & 63;

    // swizzled block -> (bi, bj), bi <= bj, 128-row strips
    int mm = blockIdx.x >> 3;
    const int r = blockIdx.x & 7;
    int bi = 0;
    #pragma unroll
    for (int s = 0; s < 8; ++s) {
        const int strip = (s & 1) ? ((s >> 1) * 16 + 15 - r) : ((s >> 1) * 16 + r);
        const int n = 64 - strip;
        if (mm < n) { bi = strip; break; }
        mm -= n;
    }
    const int bj = bi + mm;
    const bool diag = (bi == bj);

    if (t < 128) { rpart[t] = 0.0f; cpart[t] = 0.0f; }

    // 4 glds units (1 KB each) per wave: g in {w, w+4, w+8, w+12}
    const u8* gsrc[4];
    int ldst[4];
    #pragma unroll
    for (int gg = 0; gg < 4; ++gg) {
        const int g = gg * 4 + w;
        const int region = g >> 3;           // 0 = A(bi), 1 = B(bj)
        const int a = (g & 7) >> 1, p = g & 1;
        const int RT = (region ? bj : bi) * 4 + a;
        gsrc[gg] = P8 + (size_t)RT * 32768 + p * 1024 + lane * 16;
        ldst[gg] = region * 8192 + a * 2048 + p * 1024;
    }

    const int qi = w >> 1, qj = w & 1;
    f32x16 acc[2][2];
    #pragma unroll
    for (int a = 0; a < 2; ++a)
        #pragma unroll
        for (int b = 0; b < 2; ++b)
            #pragma unroll
            for (int e = 0; e < 16; ++e) acc[a][b][e] = 0.0f;

    // prologue: stage chunk 0 into buffer 0
    #pragma unroll
    for (int gg = 0; gg < 4; ++gg)
        __builtin_amdgcn_global_load_lds(GLOBAL_AS(gsrc[gg]),
                                         LDS_AS(&lds[0][ldst[gg]]), 16, 0, 0);

    for (int kc = 0; kc < 16; ++kc) {        // BK = 64
        const int cur = kc & 1;
        __syncthreads();   // drains own glds (chunk kc); buf cur^1 free since barrier kc-1
        if (kc < 15) {
            #pragma unroll
            for (int gg = 0; gg < 4; ++gg)
                __builtin_amdgcn_global_load_lds(GLOBAL_AS(gsrc[gg] + (size_t)(kc + 1) * 2048),
                                                 LDS_AS(&lds[cur ^ 1][ldst[gg]]), 16, 0, 0);
        }
        #pragma unroll
        for (int kk = 0; kk < 4; ++kk) {     // 4 K-steps of K=16
            long af[2], bf[2];
            #pragma unroll
            for (int ti = 0; ti < 2; ++ti)
                af[ti] = *(const long*)&lds[cur][((qi * 2 + ti) * 4 + kk) * 512 + lane * 8];
            #pragma unroll
            for (int tj = 0; tj < 2; ++tj)
                bf[tj] = *(const long*)&lds[cur][8192 + ((qj * 2 + tj) * 4 + kk) * 512 + lane * 8];
            #pragma unroll
            for (int ti = 0; ti < 2; ++ti)
                #pragma unroll
                for (int tj = 0; tj < 2; ++tj)
                    acc[ti][tj] = __builtin_amdgcn_mfma_f32_32x32x16_fp8_fp8(
                        af[ti], bf[tj], acc[ti][tj], 0, 0, 0);
        }
    }

    // epilogue: exp(acc*10/64), diag-block triangle mask, row/col partials
    // C layout (32x32): col = lane&31, row = (reg&3) + 8*(reg>>2) + 4*(lane>>5)
    __syncthreads();   // last chunk's frag reads done; rpart/cpart ready
    const int half = lane >> 5, col = lane & 31;
    float csum[2] = {0.0f, 0.0f};
    #pragma unroll
    for (int ti = 0; ti < 2; ++ti) {
        float rs[16];
        #pragma unroll
        for (int reg = 0; reg < 16; ++reg) rs[reg] = 0.0f;
        #pragma unroll
        for (int tj = 0; tj < 2; ++tj) {
            const int lj = qj * 64 + tj * 32 + col;
            #pragma unroll
            for (int reg = 0; reg < 16; ++reg) {
                const int li = qi * 64 + ti * 32 + (reg & 3) + 8 * (reg >> 2) + 4 * half;
                float e = __expf(acc[ti][tj][reg] * INVT_SCALED);
                if (diag && li >= lj) e = 0.0f;      // bi<bj blocks: always li<lj globally
                rs[reg] += e;
                csum[tj] += e;
            }
        }
        #pragma unroll
        for (int reg = 0; reg < 16; ++reg) {
            float v = rs[reg];
            v += __shfl_xor(v, 1); v += __shfl_xor(v, 2); v += __shfl_xor(v, 4);
            v += __shfl_xor(v, 8); v += __shfl_xor(v, 16);
            if (col == 0)
                atomicAdd(&rpart[qi * 64 + ti * 32 + (reg & 3) + 8 * (reg >> 2) + 4 * half], v);
        }
    }
    #pragma unroll
    for (int tj = 0; tj < 2; ++tj) {
        float v = csum[tj];
        v += __shfl_xor(v, 32);
        if (half == 0) atomicAdd(&cpart[qj * 64 + tj * 32 + col], v);
    }
    __syncthreads();
    if (t < 128) atomicAdd(&rowsum[bi * 128 + t], rpart[t]);
    else         atomicAdd(&rowsum[bj * 128 + (t - 128)], cpart[t - 128]);
}

// ---------------------------------------------------------------------------
// rowsum == sum_neg (diag + lower triangle excluded in gram)
__global__ __launch_bounds__(256) void final2_kernel(const float* __restrict__ rowsum,
                                                     float* __restrict__ out) {
    __shared__ float red[4];
    const int t = threadIdx.x;
    const int i = blockIdx.x * 256 + t;
    float v = logf(rowsum[i] * (1.0f / (float)(C - 1)));
    #pragma unroll
    for (int off = 32; off > 0; off >>= 1) v += __shfl_down(v, off);
    if ((t & 63) == 0) red[t >> 6] = v;
    __syncthreads();
    if (t == 0)
        atomicAdd(out, (red[0] + red[1] + red[2] + red[3]) * (1.0f / (float)C));
}

// ---------------------------------------------------------------------------
extern "C" void kernel_launch(void* const* d_in, const int* in_sizes, int n_in,
                              void* d_out, int out_size, void* d_ws, size_t ws_size,
                              hipStream_t stream) {
    const float* feat = (const float*)d_in[0];
    const int* labels = (const int*)d_in[1];
    const float* protos = (const float*)d_in[2];
    float* out = (float*)d_out;
    float* rowsum = (float*)d_ws;               // 32 KB
    u8* P8 = (u8*)((char*)d_ws + 32768);        // 8 MiB packed fp8 protos

    ema_split_kernel<<<C / 4, 256, 0, stream>>>(feat, labels, protos, P8, rowsum, out);
    gram8_kernel<<<2080, 256, 0, stream>>>(P8, rowsum);
    final2_kernel<<<C / 256, 256, 0, stream>>>(rowsum, out);
}